// Round 1
// 524.757 us; speedup vs baseline: 1.5464x; 1.5464x over previous
//
#include <hip/hip_runtime.h>
#include <stdint.h>

#define E_TOTAL   500000
#define NODE_DIM  128
#define EDGE_DIM  64
#define IN_DIM    192
#define OUT_DIM_  128
#define LN_EPS    1e-5f
#define NTILES    ((E_TOTAL + 63) / 64)   // 7813 tiles of 64 rows

typedef __attribute__((ext_vector_type(8))) short  short8;
typedef __attribute__((ext_vector_type(4))) float  floatx4;
typedef __attribute__((ext_vector_type(4))) unsigned int uintx4;

union Frag { short8 s; uintx4 u; };

__device__ __forceinline__ unsigned short f2bf(float f) {
    unsigned int u = __float_as_uint(f);
    return (unsigned short)((u + 0x7FFFu + ((u >> 16) & 1u)) >> 16);  // RNE
}
__device__ __forceinline__ unsigned int pk2(float a, float b) {
    return (unsigned int)f2bf(a) | ((unsigned int)f2bf(b) << 16);
}
__device__ __forceinline__ float silu(float y) {
    return y / (1.0f + __expf(-y));
}

// LDS budget: W1 frags 49152 + ws 4*1088*4=17408 + params 2048 = 68608 B
// -> 2 blocks/CU (137216 <= 163840), 8 waves/CU = 2 waves/SIMD.
// ws[wave] is a union: bf16 hstage (16x136 shorts = 4352 B) during GEMM2,
// then fp32 out-stage (8x132 floats = 4224 B) during the store epilogue.
__launch_bounds__(256, 2)
__global__ void edge_mlp_kernel(
    const float* __restrict__ src,   // E x 128
    const float* __restrict__ edg,   // E x 64
    const float* __restrict__ W1,    // 192 x 128 (K x N)
    const float* __restrict__ b1,    // 128
    const float* __restrict__ gam,   // 128
    const float* __restrict__ bet,   // 128
    const float* __restrict__ W2,    // 128 x 128 (K x N)
    const float* __restrict__ b2,    // 128
    float* __restrict__ out)         // E x 128
{
    __shared__ uintx4 w1f[48 * 64];                        // 48 B-frags (s=0..5, t=0..7)
    __shared__ __align__(16) float ws[4][1088];            // per-wave scratch (see above)
    __shared__ float pl[512];                              // b1 | gamma | beta | b2

    const int tid  = threadIdx.x;
    const int lane = tid & 63;
    const int wave = tid >> 6;
    const int quad = lane >> 4;
    const int l15  = lane & 15;

    // ---- stage W1 as bf16 B-fragments: frag f=s*8+t, lane entry holds
    //      W1[k = s*32 + quad*8 + j][n = t*16 + l15], j=0..7
    #pragma unroll
    for (int i = 0; i < 12; ++i) {
        int f = wave + 4 * i;            // each wave covers 12 of 48 frags
        int s = f >> 3, t = f & 7;
        const float* wp = W1 + (size_t)(s * 32 + quad * 8) * OUT_DIM_ + t * 16 + l15;
        uintx4 v;
        v.x = pk2(wp[0],            wp[OUT_DIM_]);
        v.y = pk2(wp[2 * OUT_DIM_], wp[3 * OUT_DIM_]);
        v.z = pk2(wp[4 * OUT_DIM_], wp[5 * OUT_DIM_]);
        v.w = pk2(wp[6 * OUT_DIM_], wp[7 * OUT_DIM_]);
        w1f[f * 64 + lane] = v;
    }
    // ---- params into LDS
    pl[tid]       = (tid < 128) ? b1[tid]  : gam[tid - 128];
    pl[256 + tid] = (tid < 128) ? bet[tid] : b2[tid - 128];

    // ---- W2 bf16 B-fragments in registers (32 frags x 16 B = 128 regs)
    Frag w2r[32];
    #pragma unroll
    for (int f = 0; f < 32; ++f) {
        int s = f >> 3, t = f & 7;
        const float* wp = W2 + (size_t)(s * 32 + quad * 8) * OUT_DIM_ + t * 16 + l15;
        w2r[f].u.x = pk2(wp[0],            wp[OUT_DIM_]);
        w2r[f].u.y = pk2(wp[2 * OUT_DIM_], wp[3 * OUT_DIM_]);
        w2r[f].u.z = pk2(wp[4 * OUT_DIM_], wp[5 * OUT_DIM_]);
        w2r[f].u.w = pk2(wp[6 * OUT_DIM_], wp[7 * OUT_DIM_]);
    }
    __syncthreads();

    unsigned short* hst = (unsigned short*)&ws[wave][0];
    float*          ost = &ws[wave][0];

    // ---- software-pipelined A: prefetch tile0 into registers
    int tile = blockIdx.x;
    floatx4 nx[12];
    {
        int r = tile * 64 + wave * 16 + l15;
        int rc = r < E_TOTAL ? r : (E_TOTAL - 1);
        const float* sp = src + (size_t)rc * NODE_DIM + quad * 8;
        const float* ep = edg + (size_t)rc * EDGE_DIM + quad * 8;
        #pragma unroll
        for (int s = 0; s < 4; ++s) {
            nx[2 * s]     = *(const floatx4*)(sp + s * 32);
            nx[2 * s + 1] = *(const floatx4*)(sp + s * 32 + 4);
        }
        #pragma unroll
        for (int s = 0; s < 2; ++s) {
            nx[8 + 2 * s] = *(const floatx4*)(ep + s * 32);
            nx[9 + 2 * s] = *(const floatx4*)(ep + s * 32 + 4);
        }
    }

    for (; tile < NTILES; tile += gridDim.x) {
        const int rbase = tile * 64 + wave * 16;

        floatx4 acc[8];
        #pragma unroll
        for (int t = 0; t < 8; ++t) acc[t] = (floatx4)(0.0f);

        // ---- GEMM1: 6 K-steps of 32, A from prefetched registers
        #pragma unroll
        for (int s = 0; s < 6; ++s) {
            floatx4 x0 = nx[2 * s];
            floatx4 x1 = nx[2 * s + 1];
            Frag a;
            a.u.x = pk2(x0.x, x0.y);
            a.u.y = pk2(x0.z, x0.w);
            a.u.z = pk2(x1.x, x1.y);
            a.u.w = pk2(x1.z, x1.w);
            #pragma unroll
            for (int t = 0; t < 8; ++t) {
                Frag w; w.u = w1f[(s * 8 + t) * 64 + lane];
                acc[t] = __builtin_amdgcn_mfma_f32_16x16x32_bf16(a.s, w.s, acc[t], 0, 0, 0);
            }
        }

        // ---- issue next tile's A-loads now; latency hides under LN+GEMM2+stores
        {
            int tn = tile + gridDim.x;
            if (tn < NTILES) {
                int r = tn * 64 + wave * 16 + l15;
                int rc = r < E_TOTAL ? r : (E_TOTAL - 1);
                const float* sp = src + (size_t)rc * NODE_DIM + quad * 8;
                const float* ep = edg + (size_t)rc * EDGE_DIM + quad * 8;
                #pragma unroll
                for (int s = 0; s < 4; ++s) {
                    nx[2 * s]     = *(const floatx4*)(sp + s * 32);
                    nx[2 * s + 1] = *(const floatx4*)(sp + s * 32 + 4);
                }
                #pragma unroll
                for (int s = 0; s < 2; ++s) {
                    nx[8 + 2 * s] = *(const floatx4*)(ep + s * 32);
                    nx[9 + 2 * s] = *(const floatx4*)(ep + s * 32 + 4);
                }
            }
        }

        // ---- + b1, LayerNorm stats (rows = quad*4+j, cols = t*16+l15)
        float S1[4] = {0, 0, 0, 0}, S2[4] = {0, 0, 0, 0};
        #pragma unroll
        for (int t = 0; t < 8; ++t) {
            float bb = pl[t * 16 + l15];
            #pragma unroll
            for (int j = 0; j < 4; ++j) {
                float h = acc[t][j] + bb;
                acc[t][j] = h;
                S1[j] += h;
                S2[j] += h * h;
            }
        }
        #pragma unroll
        for (int m = 1; m < 16; m <<= 1) {
            #pragma unroll
            for (int j = 0; j < 4; ++j) {
                S1[j] += __shfl_xor(S1[j], m, 64);
                S2[j] += __shfl_xor(S2[j], m, 64);
            }
        }
        float mu[4], rs[4];
        #pragma unroll
        for (int j = 0; j < 4; ++j) {
            mu[j] = S1[j] * (1.0f / 128.0f);
            float var = S2[j] * (1.0f / 128.0f) - mu[j] * mu[j];
            rs[j] = rsqrtf(var + LN_EPS);
        }

        // ---- normalize + affine + SiLU, stage as bf16 in A-layout-friendly rows
        #pragma unroll
        for (int t = 0; t < 8; ++t) {
            float g  = pl[128 + t * 16 + l15];
            float bt = pl[256 + t * 16 + l15];
            #pragma unroll
            for (int j = 0; j < 4; ++j) {
                float y = (acc[t][j] - mu[j]) * rs[j] * g + bt;
                hst[(quad * 4 + j) * 136 + t * 16 + l15] = f2bf(silu(y));
            }
        }

        // ---- GEMM2: 4 K-steps of 32, A from hstage (wave-private, no barrier)
        #pragma unroll
        for (int t = 0; t < 8; ++t) acc[t] = (floatx4)(0.0f);
        #pragma unroll
        for (int s2 = 0; s2 < 4; ++s2) {
            Frag a2;
            a2.u = *(const uintx4*)&hst[l15 * 136 + s2 * 32 + quad * 8];
            #pragma unroll
            for (int t = 0; t < 8; ++t) {
                acc[t] = __builtin_amdgcn_mfma_f32_16x16x32_bf16(a2.s, w2r[s2 * 8 + t].s, acc[t], 0, 0, 0);
            }
        }

        // ---- + b2, SiLU, stage fp32 in LDS, store full 128B lines (2 passes of 8 rows)
        #pragma unroll
        for (int p = 0; p < 2; ++p) {
            #pragma unroll
            for (int t = 0; t < 8; ++t) {
                float bb2 = pl[384 + t * 16 + l15];
                #pragma unroll
                for (int jj = 0; jj < 2; ++jj) {
                    float y = acc[t][2 * p + jj] + bb2;
                    // local row = quad*2 + jj (0..7), row stride 132 floats
                    ost[(quad * 2 + jj) * 132 + t * 16 + l15] = silu(y);
                }
            }
            // read back row-contiguous: lane covers row a = lane>>3, chunk b = lane&7
            {
                int a = lane >> 3;
                int b = lane & 7;
                int grow = rbase + (a >> 1) * 4 + 2 * p + (a & 1);
                if (grow < E_TOTAL) {
                    const float* rp = ost + a * 132 + b * 4;
                    float* op = out + (size_t)grow * OUT_DIM_ + b * 4;
                    #pragma unroll
                    for (int c = 0; c < 4; ++c) {
                        *(floatx4*)(op + 32 * c) = *(const floatx4*)(rp + 32 * c);
                    }
                }
            }
        }
    }
}

extern "C" void kernel_launch(void* const* d_in, const int* in_sizes, int n_in,
                              void* d_out, int out_size, void* d_ws, size_t ws_size,
                              hipStream_t stream) {
    const float* src = (const float*)d_in[0];
    const float* edg = (const float*)d_in[1];
    const float* W1  = (const float*)d_in[2];
    const float* b1  = (const float*)d_in[3];
    const float* gam = (const float*)d_in[4];
    const float* bet = (const float*)d_in[5];
    const float* W2  = (const float*)d_in[6];
    const float* b2  = (const float*)d_in[7];
    float* out = (float*)d_out;

    edge_mlp_kernel<<<512, 256, 0, stream>>>(src, edg, W1, b1, gam, bet, W2, b2, out);
}

// Round 2
// 524.740 us; speedup vs baseline: 1.5464x; 1.0000x over previous
//
#include <hip/hip_runtime.h>
#include <stdint.h>

#define E_TOTAL   500000
#define NODE_DIM  128
#define EDGE_DIM  64
#define IN_DIM    192
#define OUT_DIM_  128
#define LN_EPS    1e-5f
#define NTILES    ((E_TOTAL + 63) / 64)   // 7813 tiles of 64 rows

typedef __attribute__((ext_vector_type(8))) short  short8;
typedef __attribute__((ext_vector_type(4))) float  floatx4;
typedef __attribute__((ext_vector_type(4))) unsigned int uintx4;

union Frag { short8 s; uintx4 u; };

// HW packed f32->bf16 (RNE), 1 instruction instead of ~11 VALU ops.
__device__ __forceinline__ unsigned int cvtpk(float a, float b) {
    unsigned int r;
    asm("v_cvt_pk_bf16_f32 %0, %1, %2" : "=v"(r) : "v"(a), "v"(b));
    return r;
}
__device__ __forceinline__ unsigned short f2bf1(float a) {
    unsigned int r;
    asm("v_cvt_pk_bf16_f32 %0, %1, %1" : "=v"(r) : "v"(a));
    return (unsigned short)r;
}
__device__ __forceinline__ float silu(float y) {
    return y / (1.0f + __expf(-y));
}

// LDS budget: W1 frags 49152 + ws 4*1088*4=17408 + params 2048 = 68608 B
// -> 2 blocks/CU (137216 <= 163840), 8 waves/CU = 2 waves/SIMD.
// ws[wave] union: bf16 hstage (16 rows x 136 shorts = 4352 B) during GEMM2,
// then fp32 out-stage (8 rows x 136 floats = 4352 B) during the store epilogue.
// Row stride 136 (not 132): dword stride % 32 == 8 -> ds_read_b128 start banks
// (8a+4b)%32 are only 2-way aliased (free), vs 8-way at stride 132.
__launch_bounds__(256, 2)
__global__ void edge_mlp_kernel(
    const float* __restrict__ src,   // E x 128
    const float* __restrict__ edg,   // E x 64
    const float* __restrict__ W1,    // 192 x 128 (K x N)
    const float* __restrict__ b1,    // 128
    const float* __restrict__ gam,   // 128
    const float* __restrict__ bet,   // 128
    const float* __restrict__ W2,    // 128 x 128 (K x N)
    const float* __restrict__ b2,    // 128
    float* __restrict__ out)         // E x 128
{
    __shared__ uintx4 w1f[48 * 64];                        // 48 B-frags (s=0..5, t=0..7)
    __shared__ __align__(16) float ws[4][1088];            // per-wave scratch (see above)
    __shared__ float pl[512];                              // b1 | gamma | beta | b2

    const int tid  = threadIdx.x;
    const int lane = tid & 63;
    const int wave = tid >> 6;
    const int quad = lane >> 4;
    const int l15  = lane & 15;

    // ---- stage W1 as bf16 B-fragments: frag f=s*8+t, lane entry holds
    //      W1[k = s*32 + quad*8 + j][n = t*16 + l15], j=0..7
    #pragma unroll
    for (int i = 0; i < 12; ++i) {
        int f = wave + 4 * i;            // each wave covers 12 of 48 frags
        int s = f >> 3, t = f & 7;
        const float* wp = W1 + (size_t)(s * 32 + quad * 8) * OUT_DIM_ + t * 16 + l15;
        uintx4 v;
        v.x = cvtpk(wp[0],            wp[OUT_DIM_]);
        v.y = cvtpk(wp[2 * OUT_DIM_], wp[3 * OUT_DIM_]);
        v.z = cvtpk(wp[4 * OUT_DIM_], wp[5 * OUT_DIM_]);
        v.w = cvtpk(wp[6 * OUT_DIM_], wp[7 * OUT_DIM_]);
        w1f[f * 64 + lane] = v;
    }
    // ---- params into LDS
    pl[tid]       = (tid < 128) ? b1[tid]  : gam[tid - 128];
    pl[256 + tid] = (tid < 128) ? bet[tid] : b2[tid - 128];

    // ---- W2 bf16 B-fragments in registers (32 frags x 16 B = 128 regs)
    Frag w2r[32];
    #pragma unroll
    for (int f = 0; f < 32; ++f) {
        int s = f >> 3, t = f & 7;
        const float* wp = W2 + (size_t)(s * 32 + quad * 8) * OUT_DIM_ + t * 16 + l15;
        w2r[f].u.x = cvtpk(wp[0],            wp[OUT_DIM_]);
        w2r[f].u.y = cvtpk(wp[2 * OUT_DIM_], wp[3 * OUT_DIM_]);
        w2r[f].u.z = cvtpk(wp[4 * OUT_DIM_], wp[5 * OUT_DIM_]);
        w2r[f].u.w = cvtpk(wp[6 * OUT_DIM_], wp[7 * OUT_DIM_]);
    }
    __syncthreads();

    unsigned short* hst = (unsigned short*)&ws[wave][0];
    float*          ost = &ws[wave][0];

    // ---- software-pipelined A: prefetch tile0 into registers
    int tile = blockIdx.x;
    floatx4 nx[12];
    {
        int r = tile * 64 + wave * 16 + l15;
        int rc = r < E_TOTAL ? r : (E_TOTAL - 1);
        const float* sp = src + (size_t)rc * NODE_DIM + quad * 8;
        const float* ep = edg + (size_t)rc * EDGE_DIM + quad * 8;
        #pragma unroll
        for (int s = 0; s < 4; ++s) {
            nx[2 * s]     = *(const floatx4*)(sp + s * 32);
            nx[2 * s + 1] = *(const floatx4*)(sp + s * 32 + 4);
        }
        #pragma unroll
        for (int s = 0; s < 2; ++s) {
            nx[8 + 2 * s] = *(const floatx4*)(ep + s * 32);
            nx[9 + 2 * s] = *(const floatx4*)(ep + s * 32 + 4);
        }
    }

    for (; tile < NTILES; tile += gridDim.x) {
        const int rbase = tile * 64 + wave * 16;

        floatx4 acc[8];
        #pragma unroll
        for (int t = 0; t < 8; ++t) acc[t] = (floatx4)(0.0f);

        // ---- GEMM1: 6 K-steps of 32, A from prefetched registers
        #pragma unroll
        for (int s = 0; s < 6; ++s) {
            floatx4 x0 = nx[2 * s];
            floatx4 x1 = nx[2 * s + 1];
            Frag a;
            a.u.x = cvtpk(x0.x, x0.y);
            a.u.y = cvtpk(x0.z, x0.w);
            a.u.z = cvtpk(x1.x, x1.y);
            a.u.w = cvtpk(x1.z, x1.w);
            #pragma unroll
            for (int t = 0; t < 8; ++t) {
                Frag w; w.u = w1f[(s * 8 + t) * 64 + lane];
                acc[t] = __builtin_amdgcn_mfma_f32_16x16x32_bf16(a.s, w.s, acc[t], 0, 0, 0);
            }
        }

        // ---- issue next tile's A-loads now; latency hides under LN+GEMM2+stores
        {
            int tn = tile + gridDim.x;
            if (tn < NTILES) {
                int r = tn * 64 + wave * 16 + l15;
                int rc = r < E_TOTAL ? r : (E_TOTAL - 1);
                const float* sp = src + (size_t)rc * NODE_DIM + quad * 8;
                const float* ep = edg + (size_t)rc * EDGE_DIM + quad * 8;
                #pragma unroll
                for (int s = 0; s < 4; ++s) {
                    nx[2 * s]     = *(const floatx4*)(sp + s * 32);
                    nx[2 * s + 1] = *(const floatx4*)(sp + s * 32 + 4);
                }
                #pragma unroll
                for (int s = 0; s < 2; ++s) {
                    nx[8 + 2 * s] = *(const floatx4*)(ep + s * 32);
                    nx[9 + 2 * s] = *(const floatx4*)(ep + s * 32 + 4);
                }
            }
        }

        // ---- + b1, LayerNorm stats (rows = quad*4+j, cols = t*16+l15)
        float S1[4] = {0, 0, 0, 0}, S2[4] = {0, 0, 0, 0};
        #pragma unroll
        for (int t = 0; t < 8; ++t) {
            float bb = pl[t * 16 + l15];
            #pragma unroll
            for (int j = 0; j < 4; ++j) {
                float h = acc[t][j] + bb;
                acc[t][j] = h;
                S1[j] += h;
                S2[j] += h * h;
            }
        }
        #pragma unroll
        for (int m = 1; m < 16; m <<= 1) {
            #pragma unroll
            for (int j = 0; j < 4; ++j) {
                S1[j] += __shfl_xor(S1[j], m, 64);
                S2[j] += __shfl_xor(S2[j], m, 64);
            }
        }
        float mu[4], rs[4];
        #pragma unroll
        for (int j = 0; j < 4; ++j) {
            mu[j] = S1[j] * (1.0f / 128.0f);
            float var = S2[j] * (1.0f / 128.0f) - mu[j] * mu[j];
            rs[j] = rsqrtf(var + LN_EPS);
        }

        // ---- normalize + affine + SiLU, stage as bf16 in A-layout-friendly rows
        #pragma unroll
        for (int t = 0; t < 8; ++t) {
            float g  = pl[128 + t * 16 + l15];
            float bt = pl[256 + t * 16 + l15];
            #pragma unroll
            for (int j = 0; j < 4; ++j) {
                float y = (acc[t][j] - mu[j]) * rs[j] * g + bt;
                hst[(quad * 4 + j) * 136 + t * 16 + l15] = f2bf1(silu(y));
            }
        }

        // ---- GEMM2: 4 K-steps of 32, A from hstage (wave-private, no barrier)
        #pragma unroll
        for (int t = 0; t < 8; ++t) acc[t] = (floatx4)(0.0f);
        #pragma unroll
        for (int s2 = 0; s2 < 4; ++s2) {
            Frag a2;
            a2.u = *(const uintx4*)&hst[l15 * 136 + s2 * 32 + quad * 8];
            #pragma unroll
            for (int t = 0; t < 8; ++t) {
                acc[t] = __builtin_amdgcn_mfma_f32_16x16x32_bf16(a2.s, w2r[s2 * 8 + t].s, acc[t], 0, 0, 0);
            }
        }

        // ---- + b2, SiLU, stage fp32 in LDS, store full 128B lines (2 passes of 8 rows)
        #pragma unroll
        for (int p = 0; p < 2; ++p) {
            #pragma unroll
            for (int t = 0; t < 8; ++t) {
                float bb2 = pl[384 + t * 16 + l15];
                #pragma unroll
                for (int jj = 0; jj < 2; ++jj) {
                    float y = acc[t][2 * p + jj] + bb2;
                    // local row = quad*2 + jj (0..7), row stride 136 floats
                    ost[(quad * 2 + jj) * 136 + t * 16 + l15] = silu(y);
                }
            }
            // read back row-contiguous: lane covers row a = lane>>3, chunk b = lane&7
            {
                int a = lane >> 3;
                int b = lane & 7;
                int grow = rbase + (a >> 1) * 4 + 2 * p + (a & 1);
                if (grow < E_TOTAL) {
                    const float* rp = ost + a * 136 + b * 4;
                    float* op = out + (size_t)grow * OUT_DIM_ + b * 4;
                    #pragma unroll
                    for (int c = 0; c < 4; ++c) {
                        *(floatx4*)(op + 32 * c) = *(const floatx4*)(rp + 32 * c);
                    }
                }
            }
        }
    }
}

extern "C" void kernel_launch(void* const* d_in, const int* in_sizes, int n_in,
                              void* d_out, int out_size, void* d_ws, size_t ws_size,
                              hipStream_t stream) {
    const float* src = (const float*)d_in[0];
    const float* edg = (const float*)d_in[1];
    const float* W1  = (const float*)d_in[2];
    const float* b1  = (const float*)d_in[3];
    const float* gam = (const float*)d_in[4];
    const float* bet = (const float*)d_in[5];
    const float* W2  = (const float*)d_in[6];
    const float* b2  = (const float*)d_in[7];
    float* out = (float*)d_out;

    edge_mlp_kernel<<<512, 256, 0, stream>>>(src, edg, W1, b1, gam, bet, W2, b2, out);
}

// Round 4
// 518.008 us; speedup vs baseline: 1.5665x; 1.0130x over previous
//
#include <hip/hip_runtime.h>
#include <stdint.h>

#define E_TOTAL   500000
#define NODE_DIM  128
#define EDGE_DIM  64
#define IN_DIM    192
#define OUT_DIM_  128
#define LN_EPS    1e-5f
#define NTILES    ((E_TOTAL + 63) / 64)   // 7813 tiles of 64 rows

typedef __attribute__((ext_vector_type(8))) short  short8;
typedef __attribute__((ext_vector_type(4))) float  floatx4;
typedef __attribute__((ext_vector_type(4))) unsigned int uintx4;

union Frag { short8 s; uintx4 u; };

// HW packed f32->bf16 (RNE), 1 instruction.
__device__ __forceinline__ unsigned int cvtpk(float a, float b) {
    unsigned int r;
    asm("v_cvt_pk_bf16_f32 %0, %1, %2" : "=v"(r) : "v"(a), "v"(b));
    return r;
}
__device__ __forceinline__ unsigned short f2bf1(float a) {
    unsigned int r;
    asm("v_cvt_pk_bf16_f32 %0, %1, %1" : "=v"(r) : "v"(a));
    return (unsigned short)r;
}
// Raw transcendentals (~1 ulp) — tolerance is bf16-scale (absmax 0.0078),
// so skip the non-fast-math IEEE div/exp fixup expansions (~15 VALU ops each).
__device__ __forceinline__ float fexp2(float x) {
    float r; asm("v_exp_f32 %0, %1" : "=v"(r) : "v"(x)); return r;
}
__device__ __forceinline__ float frcp(float x) {
    float r; asm("v_rcp_f32 %0, %1" : "=v"(r) : "v"(x)); return r;
}
__device__ __forceinline__ float frsq(float x) {
    float r; asm("v_rsq_f32 %0, %1" : "=v"(r) : "v"(x)); return r;
}
// silu = y * sigmoid(y) = y * rcp(1 + 2^(-y*log2e)) : 5 VALU (2 trans)
__device__ __forceinline__ float silu(float y) {
    return y * frcp(1.0f + fexp2(y * -1.44269504f));
}

// LDS budget: W1 frags 49152 + ws 4*1088*4=17408 + params 2048 = 68608 B
// -> 2 blocks/CU (137216 <= 163840), 8 waves/CU = 2 waves/SIMD.
// ws[wave] union: bf16 hstage (16 rows x 136 shorts = 4352 B) during GEMM2,
// then fp32 out-stage (8 rows x 136 floats = 4352 B) during the store epilogue.
// Row stride 136: dword stride % 32 == 8 -> ds_read_b128 start banks only
// 2-way aliased (free).
__launch_bounds__(256, 2)
__global__ void edge_mlp_kernel(
    const float* __restrict__ src,   // E x 128
    const float* __restrict__ edg,   // E x 64
    const float* __restrict__ W1,    // 192 x 128 (K x N)
    const float* __restrict__ b1,    // 128
    const float* __restrict__ gam,   // 128
    const float* __restrict__ bet,   // 128
    const float* __restrict__ W2,    // 128 x 128 (K x N)
    const float* __restrict__ b2,    // 128
    float* __restrict__ out)         // E x 128
{
    __shared__ uintx4 w1f[48 * 64];                        // 48 B-frags (s=0..5, t=0..7)
    __shared__ __align__(16) float ws[4][1088];            // per-wave scratch (see above)
    __shared__ float pl[512];                              // b1 | gamma | beta | b2

    const int tid  = threadIdx.x;
    const int lane = tid & 63;
    const int wave = tid >> 6;
    const int quad = lane >> 4;
    const int l15  = lane & 15;

    // ---- stage W1 as bf16 B-fragments: frag f=s*8+t, lane entry holds
    //      W1[k = s*32 + quad*8 + j][n = t*16 + l15], j=0..7
    #pragma unroll
    for (int i = 0; i < 12; ++i) {
        int f = wave + 4 * i;            // each wave covers 12 of 48 frags
        int s = f >> 3, t = f & 7;
        const float* wp = W1 + (size_t)(s * 32 + quad * 8) * OUT_DIM_ + t * 16 + l15;
        uintx4 v;
        v.x = cvtpk(wp[0],            wp[OUT_DIM_]);
        v.y = cvtpk(wp[2 * OUT_DIM_], wp[3 * OUT_DIM_]);
        v.z = cvtpk(wp[4 * OUT_DIM_], wp[5 * OUT_DIM_]);
        v.w = cvtpk(wp[6 * OUT_DIM_], wp[7 * OUT_DIM_]);
        w1f[f * 64 + lane] = v;
    }
    // ---- params into LDS
    pl[tid]       = (tid < 128) ? b1[tid]  : gam[tid - 128];
    pl[256 + tid] = (tid < 128) ? bet[tid] : b2[tid - 128];

    // ---- W2 bf16 B-fragments in registers (32 frags x 16 B = 128 regs)
    Frag w2r[32];
    #pragma unroll
    for (int f = 0; f < 32; ++f) {
        int s = f >> 3, t = f & 7;
        const float* wp = W2 + (size_t)(s * 32 + quad * 8) * OUT_DIM_ + t * 16 + l15;
        w2r[f].u.x = cvtpk(wp[0],            wp[OUT_DIM_]);
        w2r[f].u.y = cvtpk(wp[2 * OUT_DIM_], wp[3 * OUT_DIM_]);
        w2r[f].u.z = cvtpk(wp[4 * OUT_DIM_], wp[5 * OUT_DIM_]);
        w2r[f].u.w = cvtpk(wp[6 * OUT_DIM_], wp[7 * OUT_DIM_]);
    }
    __syncthreads();

    unsigned short* hst = (unsigned short*)&ws[wave][0];
    float*          ost = &ws[wave][0];

    // ---- software-pipelined A: prefetch tile0 into registers
    int tile = blockIdx.x;
    floatx4 nx[12];
    {
        int r = tile * 64 + wave * 16 + l15;
        int rc = r < E_TOTAL ? r : (E_TOTAL - 1);
        const float* sp = src + (size_t)rc * NODE_DIM + quad * 8;
        const float* ep = edg + (size_t)rc * EDGE_DIM + quad * 8;
        #pragma unroll
        for (int s = 0; s < 4; ++s) {
            nx[2 * s]     = *(const floatx4*)(sp + s * 32);
            nx[2 * s + 1] = *(const floatx4*)(sp + s * 32 + 4);
        }
        #pragma unroll
        for (int s = 0; s < 2; ++s) {
            nx[8 + 2 * s] = *(const floatx4*)(ep + s * 32);
            nx[9 + 2 * s] = *(const floatx4*)(ep + s * 32 + 4);
        }
    }

    for (; tile < NTILES; tile += gridDim.x) {
        const int rbase = tile * 64 + wave * 16;

        // ---- init GEMM1 acc with b1 broadcast (deletes the later bias-add pass)
        floatx4 acc[8];
        #pragma unroll
        for (int t = 0; t < 8; ++t) {
            float bb = pl[t * 16 + l15];
            acc[t] = (floatx4)(bb);
        }

        // ---- GEMM1: 6 K-steps of 32, A from prefetched registers
        #pragma unroll
        for (int s = 0; s < 6; ++s) {
            floatx4 x0 = nx[2 * s];
            floatx4 x1 = nx[2 * s + 1];
            Frag a;
            a.u.x = cvtpk(x0.x, x0.y);
            a.u.y = cvtpk(x0.z, x0.w);
            a.u.z = cvtpk(x1.x, x1.y);
            a.u.w = cvtpk(x1.z, x1.w);
            #pragma unroll
            for (int t = 0; t < 8; ++t) {
                Frag w; w.u = w1f[(s * 8 + t) * 64 + lane];
                acc[t] = __builtin_amdgcn_mfma_f32_16x16x32_bf16(a.s, w.s, acc[t], 0, 0, 0);
            }
        }

        // ---- issue next tile's A-loads now; latency hides under LN+GEMM2+stores
        {
            int tn = tile + gridDim.x;
            if (tn < NTILES) {
                int r = tn * 64 + wave * 16 + l15;
                int rc = r < E_TOTAL ? r : (E_TOTAL - 1);
                const float* sp = src + (size_t)rc * NODE_DIM + quad * 8;
                const float* ep = edg + (size_t)rc * EDGE_DIM + quad * 8;
                #pragma unroll
                for (int s = 0; s < 4; ++s) {
                    nx[2 * s]     = *(const floatx4*)(sp + s * 32);
                    nx[2 * s + 1] = *(const floatx4*)(sp + s * 32 + 4);
                }
                #pragma unroll
                for (int s = 0; s < 2; ++s) {
                    nx[8 + 2 * s] = *(const floatx4*)(ep + s * 32);
                    nx[9 + 2 * s] = *(const floatx4*)(ep + s * 32 + 4);
                }
            }
        }

        // ---- LayerNorm stats (h already includes b1)
        float S1[4] = {0, 0, 0, 0}, S2[4] = {0, 0, 0, 0};
        #pragma unroll
        for (int t = 0; t < 8; ++t) {
            #pragma unroll
            for (int j = 0; j < 4; ++j) {
                float h = acc[t][j];
                S1[j] += h;
                S2[j] += h * h;
            }
        }
        #pragma unroll
        for (int m = 1; m < 16; m <<= 1) {
            #pragma unroll
            for (int j = 0; j < 4; ++j) {
                S1[j] += __shfl_xor(S1[j], m, 64);
                S2[j] += __shfl_xor(S2[j], m, 64);
            }
        }
        float mu[4], rs[4];
        #pragma unroll
        for (int j = 0; j < 4; ++j) {
            mu[j] = S1[j] * (1.0f / 128.0f);
            float var = S2[j] * (1.0f / 128.0f) - mu[j] * mu[j];
            rs[j] = frsq(var + LN_EPS);
        }

        // ---- normalize (folded fma) + SiLU, stage as bf16
        #pragma unroll
        for (int t = 0; t < 8; ++t) {
            float g  = pl[128 + t * 16 + l15];
            float bt = pl[256 + t * 16 + l15];
            #pragma unroll
            for (int j = 0; j < 4; ++j) {
                float gs  = rs[j] * g;
                float off = __builtin_fmaf(-mu[j], gs, bt);
                float y   = __builtin_fmaf(acc[t][j], gs, off);
                hst[(quad * 4 + j) * 136 + t * 16 + l15] = f2bf1(silu(y));
            }
        }

        // ---- init GEMM2 acc with b2 broadcast
        #pragma unroll
        for (int t = 0; t < 8; ++t) {
            float bb2 = pl[384 + t * 16 + l15];
            acc[t] = (floatx4)(bb2);
        }
        // ---- GEMM2: 4 K-steps of 32, A from hstage (wave-private, no barrier)
        #pragma unroll
        for (int s2 = 0; s2 < 4; ++s2) {
            Frag a2;
            a2.u = *(const uintx4*)&hst[l15 * 136 + s2 * 32 + quad * 8];
            #pragma unroll
            for (int t = 0; t < 8; ++t) {
                acc[t] = __builtin_amdgcn_mfma_f32_16x16x32_bf16(a2.s, w2r[s2 * 8 + t].s, acc[t], 0, 0, 0);
            }
        }

        // ---- SiLU, stage fp32 in LDS, store full 128B lines (2 passes of 8 rows)
        #pragma unroll
        for (int p = 0; p < 2; ++p) {
            #pragma unroll
            for (int t = 0; t < 8; ++t) {
                #pragma unroll
                for (int jj = 0; jj < 2; ++jj) {
                    float y = acc[t][2 * p + jj];
                    // local row = quad*2 + jj (0..7), row stride 136 floats
                    ost[(quad * 2 + jj) * 136 + t * 16 + l15] = silu(y);
                }
            }
            // read back row-contiguous: lane covers row a = lane>>3, chunk b = lane&7
            {
                int a = lane >> 3;
                int b = lane & 7;
                int grow = rbase + (a >> 1) * 4 + 2 * p + (a & 1);
                if (grow < E_TOTAL) {
                    const float* rp = ost + a * 136 + b * 4;
                    float* op = out + (size_t)grow * OUT_DIM_ + b * 4;
                    #pragma unroll
                    for (int c = 0; c < 4; ++c) {
                        *(floatx4*)(op + 32 * c) = *(const floatx4*)(rp + 32 * c);
                    }
                }
            }
        }
    }
}

extern "C" void kernel_launch(void* const* d_in, const int* in_sizes, int n_in,
                              void* d_out, int out_size, void* d_ws, size_t ws_size,
                              hipStream_t stream) {
    const float* src = (const float*)d_in[0];
    const float* edg = (const float*)d_in[1];
    const float* W1  = (const float*)d_in[2];
    const float* b1  = (const float*)d_in[3];
    const float* gam = (const float*)d_in[4];
    const float* bet = (const float*)d_in[5];
    const float* W2  = (const float*)d_in[6];
    const float* b2  = (const float*)d_in[7];
    float* out = (float*)d_out;

    edge_mlp_kernel<<<512, 256, 0, stream>>>(src, edg, W1, b1, gam, bet, W2, b2, out);
}